// Round 2
// baseline (830.854 us; speedup 1.0000x reference)
//
#include <hip/hip_runtime.h>
#include <stdint.h>

#define IN_C 64
#define HH 256
#define WW 256
#define OUT_C 128
#define OH 254
#define OW 254
#define OHW (OH * OW)

#define XR 4     // staged input rows (2 out rows + 2 halo)
#define XW 66    // staged input width (64 + 2 halo)
#define CPAD 72  // padded channel stride: 16B-aligned b128 reads, +4-bank rotation per xx

typedef __attribute__((ext_vector_type(4))) float f32x4;
typedef __attribute__((ext_vector_type(8))) __bf16 bf16x8;

__device__ __forceinline__ unsigned short f2bf(float f) {
  union { float f; unsigned u; } v; v.f = f;
  unsigned r = v.u + 0x7FFFu + ((v.u >> 16) & 1u);  // RNE (inputs finite/normal)
  return (unsigned short)(r >> 16);
}

// Pre-shuffle weights into A-fragment order, bf16:
// wt[tap][ch][mt][lane][j] = bf16( W[o = mt*16 + (lane&15)][c = ch*32 + (lane>>4)*8 + j][ky][kx] )
// A-frag load is then a verbatim per-lane global_load_dwordx4 — no LDS staging needed.
__global__ void prep_w(const float* __restrict__ w, unsigned short* __restrict__ wt) {
  const int idx = blockIdx.x * 256 + threadIdx.x;
  if (idx >= 9 * 8192) return;
  const int j    = idx & 7;
  const int lane = (idx >> 3) & 63;
  const int mt   = (idx >> 9) & 7;
  const int ch   = (idx >> 12) & 1;
  const int tap  = idx >> 13;
  const int o = mt * 16 + (lane & 15);
  const int c = ch * 32 + (lane >> 4) * 8 + j;
  wt[idx] = f2bf(w[(o * IN_C + c) * 9 + tap]);
}

__global__ __launch_bounds__(256, 3) void conv_mfma(
    const float* __restrict__ x, const unsigned short* __restrict__ wt,
    const float* __restrict__ bias, float* __restrict__ out) {
  // Transposed input tile only: Xs[r][xx][c], c contiguous (38016 B -> 3+ blocks/CU)
  __shared__ __align__(16) unsigned short Xs[XR * XW * CPAD];

  const int tid  = threadIdx.x;
  const int wave = tid >> 6;
  const int lane = tid & 63;
  const int x0 = blockIdx.x * 64;   // 0,64,128,192 (last tile masks stores >= 254)
  const int y0 = blockIdx.y * 2;

  // ---- stage Xs: Xs[r][xx][c] = bf16(x[c][y0+r][x0+xx])
  {
    const int sc = tid >> 2;  // 0..63 : channel
    const int sq = tid & 3;   // 0..3  : 16B sub-chunk -> 4-lane 64B coalesced segments
    const float* base = x + sc * (HH * WW);
#pragma unroll
    for (int r = 0; r < XR; ++r) {
      const float* row = base + (y0 + r) * WW + x0;
#pragma unroll
      for (int xq = 0; xq < 4; ++xq) {
        const int xx = xq * 16 + sq * 4;
        const f32x4 v = *(const f32x4*)(row + xx);
#pragma unroll
        for (int i = 0; i < 4; ++i)
          Xs[(r * XW + xx + i) * CPAD + sc] = f2bf(v[i]);
      }
    }
    // tail halo xx = 64, 65 (clamped reads only feed masked out-columns on last tile)
    if (tid < 128) {
      const int c = tid & 63;
      const int xxt = 64 + (tid >> 6);
      int xg = x0 + xxt;
      if (xg > WW - 1) xg = WW - 1;
#pragma unroll
      for (int r = 0; r < XR; ++r)
        Xs[(r * XW + xxt) * CPAD + c] = f2bf(x[c * (HH * WW) + (y0 + r) * WW + xg]);
    }
  }

  const int mhalf = wave & 1;   // which half of the 128 out-channels
  const int nhalf = wave >> 1;  // which of the 2 output rows
  const int nlane = lane & 15;
  const int quad  = lane >> 4;

  // ---- accumulators, initialized with bias (C/D row = quad*4 + reg = out-ch)
  f32x4 acc[4][4];
  {
#pragma unroll
    for (int mt = 0; mt < 4; ++mt) {
      const f32x4 bv = *(const f32x4*)(bias + (mhalf * 4 + mt) * 16 + quad * 4);
#pragma unroll
      for (int nt = 0; nt < 4; ++nt) acc[mt][nt] = bv;
    }
  }

  // Per-lane A-frag pointer: frag f=(tap*2+ch)*8 + (mhalf*4+mt) lives at W8[f*64 + lane]
  const bf16x8* __restrict__ W8 = ((const bf16x8*)wt) + lane;

  // prefetch chunk 0 (tap 0, ch 0) A-frags — in flight across Xs barrier
  bf16x8 afb[2][4];
#pragma unroll
  for (int mt = 0; mt < 4; ++mt)
    afb[0][mt] = W8[(mhalf * 4 + mt) * 64];

  __syncthreads();  // Xs ready (single barrier in the kernel)

  // ---- 18 chunks = (tap, ch); A-frags prefetched one chunk ahead (no barriers,
  // MFMA <-> global_load interleave with fine-grained vmcnt)
#pragma unroll 1
  for (int chunk = 0; chunk < 18; ++chunk) {
    const int cur = chunk & 1;
    if (chunk < 17) {
      const int base = (chunk + 1) * 8 + mhalf * 4;
#pragma unroll
      for (int mt = 0; mt < 4; ++mt)
        afb[cur ^ 1][mt] = W8[(base + mt) * 64];
    }
    const int tap = chunk >> 1;
    const int ch  = chunk & 1;
    const int ky = tap / 3;
    const int kx = tap - ky * 3;
    const int r = nhalf + ky;

    bf16x8 bfr[4];
#pragma unroll
    for (int nt = 0; nt < 4; ++nt)
      bfr[nt] = *(const bf16x8*)&Xs[(r * XW + kx + nt * 16 + nlane) * CPAD + ch * 32 + quad * 8];
#pragma unroll
    for (int mt = 0; mt < 4; ++mt)
#pragma unroll
      for (int nt = 0; nt < 4; ++nt)
        acc[mt][nt] = __builtin_amdgcn_mfma_f32_16x16x32_bf16(afb[cur][mt], bfr[nt], acc[mt][nt], 0, 0, 0);
  }

  // ---- epilogue: C/D col = lane&15 (pixel), row = quad*4 + reg (out-ch); nontemporal
  const int y = y0 + nhalf;
#pragma unroll
  for (int mt = 0; mt < 4; ++mt) {
    const int obase = (mhalf * 4 + mt) * 16 + quad * 4;
#pragma unroll
    for (int nt = 0; nt < 4; ++nt) {
      const int xc = x0 + nt * 16 + nlane;
      if (xc < OW) {
        float* dst = out + obase * OHW + y * OW + xc;
#pragma unroll
        for (int reg = 0; reg < 4; ++reg)
          __builtin_nontemporal_store(acc[mt][nt][reg], dst + reg * OHW);
      }
    }
  }
}

extern "C" void kernel_launch(void* const* d_in, const int* in_sizes, int n_in,
                              void* d_out, int out_size, void* d_ws, size_t ws_size,
                              hipStream_t stream) {
  const float* x = (const float*)d_in[0];
  const float* w = (const float*)d_in[1];
  const float* b = (const float*)d_in[2];
  float* out = (float*)d_out;
  unsigned short* wt = (unsigned short*)d_ws;  // 147456 B fragment-ordered bf16 weights

  prep_w<<<dim3(288), dim3(256), 0, stream>>>(w, wt);
  conv_mfma<<<dim3(4, 127), dim3(256), 0, stream>>>(x, wt, b, out);
}

// Round 3
// 106.861 us; speedup vs baseline: 7.7751x; 7.7751x over previous
//
#include <hip/hip_runtime.h>
#include <stdint.h>

#define IN_C 64
#define HH 256
#define WW 256
#define OUT_C 128
#define OH 254
#define OW 254
#define OHW (OH * OW)

#define XR 4     // staged input rows (2 out rows + 2 halo)
#define XW 66    // staged input width (64 + 2 halo)
#define CPAD 72  // channel stride: 144 B = 9 x 16B chunks (odd) -> b128 reads conflict-free

typedef __attribute__((ext_vector_type(4))) float f32x4;
typedef __attribute__((ext_vector_type(8))) __bf16 bf16x8;

__device__ __forceinline__ unsigned short f2bf(float f) {
  union { float f; unsigned u; } v; v.f = f;
  unsigned r = v.u + 0x7FFFu + ((v.u >> 16) & 1u);  // RNE (inputs finite/normal)
  return (unsigned short)(r >> 16);
}

// Pre-shuffle weights into A-fragment order, bf16:
// wt[tap][ch][mt][lane][j] = bf16( W[o = mt*16 + (lane&15)][c = ch*32 + (lane>>4)*8 + j][ky][kx] )
// A-frag load is then a verbatim per-lane global_load_dwordx4 (L2-resident, no LDS).
__global__ void prep_w(const float* __restrict__ w, unsigned short* __restrict__ wt) {
  const int idx = blockIdx.x * 256 + threadIdx.x;
  if (idx >= 9 * 8192) return;
  const int j    = idx & 7;
  const int lane = (idx >> 3) & 63;
  const int mt   = (idx >> 9) & 7;
  const int ch   = (idx >> 12) & 1;
  const int tap  = idx >> 13;
  const int o = mt * 16 + (lane & 15);
  const int c = ch * 32 + (lane >> 4) * 8 + j;
  wt[idx] = f2bf(w[(o * IN_C + c) * 9 + tap]);
}

__global__ __launch_bounds__(256, 3) void conv_mfma(
    const float* __restrict__ x, const unsigned short* __restrict__ wt,
    const float* __restrict__ bias, float* __restrict__ out) {
  // Transposed input tile: Xs[r][xx][c], c contiguous
  __shared__ __align__(16) unsigned short Xs[XR * XW * CPAD];  // 38016 B

  const int tid  = threadIdx.x;
  const int wave = tid >> 6;
  const int lane = tid & 63;
  const int x0 = blockIdx.x * 64;   // 0,64,128,192 (last tile masks stores >= 254)
  const int y0 = blockIdx.y * 2;

  // ---- stage Xs: Xs[r][xx][c] = bf16(x[c][y0+r][x0+xx])
  {
    const int sc = tid >> 2;  // 0..63 : channel
    const int sq = tid & 3;   // 0..3  : 16B sub-chunk -> 64B coalesced segments per 4 lanes
    const float* base = x + sc * (HH * WW);
#pragma unroll
    for (int r = 0; r < XR; ++r) {
      const float* row = base + (y0 + r) * WW + x0;
#pragma unroll
      for (int xq = 0; xq < 4; ++xq) {
        const int xx = xq * 16 + sq * 4;
        const f32x4 v = *(const f32x4*)(row + xx);
#pragma unroll
        for (int i = 0; i < 4; ++i)
          Xs[(r * XW + xx + i) * CPAD + sc] = f2bf(v[i]);
      }
    }
    // tail halo xx = 64, 65 (clamped reads only feed masked out-columns on last tile)
    if (tid < 128) {
      const int c = tid & 63;
      const int xxt = 64 + (tid >> 6);
      int xg = x0 + xxt;
      if (xg > WW - 1) xg = WW - 1;
#pragma unroll
      for (int r = 0; r < XR; ++r)
        Xs[(r * XW + xxt) * CPAD + c] = f2bf(x[c * (HH * WW) + (y0 + r) * WW + xg]);
    }
  }

  const int mhalf = wave & 1;   // which half of the 128 out-channels
  const int nhalf = wave >> 1;  // which of the 2 output rows
  const int nlane = lane & 15;
  const int quad  = lane >> 4;

  // ---- accumulators initialized with bias (C/D row = quad*4 + reg = out-ch)
  f32x4 acc[4][4];
#pragma unroll
  for (int mt = 0; mt < 4; ++mt) {
    const f32x4 bv = *(const f32x4*)(bias + (mhalf * 4 + mt) * 16 + quad * 4);
#pragma unroll
    for (int nt = 0; nt < 4; ++nt) acc[mt][nt] = bv;
  }

  // Per-lane A-frag base: frag f = chunk*8 + mhalf*4 + mt at Wp[(chunk*8 + mt)*64]
  const bf16x8* __restrict__ Wp = ((const bf16x8*)wt) + lane + (mhalf * 4) * 64;

  // prefetch chunk 0 A-frags — in flight across the Xs barrier
  bf16x8 afA[4], afB[4];
#pragma unroll
  for (int mt = 0; mt < 4; ++mt) afA[mt] = Wp[mt * 64];

  __syncthreads();  // Xs ready (single barrier in the kernel)

  // ---- 9 pairs of chunks (tap = pair; ch = 0 in afA, ch = 1 in afB).
  // All buffer indices compile-time: no dynamic array indexing -> no scratch.
#pragma unroll 1
  for (int pair = 0; pair < 9; ++pair) {
    const int ky = pair / 3;
    const int kx = pair - ky * 3;
    const int r = nhalf + ky;
    const unsigned short* xrow = &Xs[(r * XW + kx) * CPAD + quad * 8];

    // prefetch odd chunk (tap=pair, ch=1)
#pragma unroll
    for (int mt = 0; mt < 4; ++mt) afB[mt] = Wp[((2 * pair + 1) * 8 + mt) * 64];

    // compute even chunk (ch = 0) with afA
    {
      bf16x8 bfr[4];
#pragma unroll
      for (int nt = 0; nt < 4; ++nt)
        bfr[nt] = *(const bf16x8*)&xrow[(nt * 16 + nlane) * CPAD];
#pragma unroll
      for (int mt = 0; mt < 4; ++mt)
#pragma unroll
        for (int nt = 0; nt < 4; ++nt)
          acc[mt][nt] = __builtin_amdgcn_mfma_f32_16x16x32_bf16(afA[mt], bfr[nt], acc[mt][nt], 0, 0, 0);
    }

    // prefetch next pair's even chunk (tap=pair+1, ch=0)
    if (pair < 8) {
#pragma unroll
      for (int mt = 0; mt < 4; ++mt) afA[mt] = Wp[((2 * pair + 2) * 8 + mt) * 64];
    }

    // compute odd chunk (ch = 1) with afB
    {
      bf16x8 bfr[4];
#pragma unroll
      for (int nt = 0; nt < 4; ++nt)
        bfr[nt] = *(const bf16x8*)&xrow[(nt * 16 + nlane) * CPAD + 32];
#pragma unroll
      for (int mt = 0; mt < 4; ++mt)
#pragma unroll
        for (int nt = 0; nt < 4; ++nt)
          acc[mt][nt] = __builtin_amdgcn_mfma_f32_16x16x32_bf16(afB[mt], bfr[nt], acc[mt][nt], 0, 0, 0);
    }
  }

  // ---- epilogue: C/D col = lane&15 (pixel), row = quad*4 + reg (out-ch); nontemporal
  const int y = y0 + nhalf;
#pragma unroll
  for (int mt = 0; mt < 4; ++mt) {
    const int obase = (mhalf * 4 + mt) * 16 + quad * 4;
#pragma unroll
    for (int nt = 0; nt < 4; ++nt) {
      const int xc = x0 + nt * 16 + nlane;
      if (xc < OW) {
        float* dst = out + obase * OHW + y * OW + xc;
#pragma unroll
        for (int reg = 0; reg < 4; ++reg)
          __builtin_nontemporal_store(acc[mt][nt][reg], dst + reg * OHW);
      }
    }
  }
}

extern "C" void kernel_launch(void* const* d_in, const int* in_sizes, int n_in,
                              void* d_out, int out_size, void* d_ws, size_t ws_size,
                              hipStream_t stream) {
  const float* x = (const float*)d_in[0];
  const float* w = (const float*)d_in[1];
  const float* b = (const float*)d_in[2];
  float* out = (float*)d_out;
  unsigned short* wt = (unsigned short*)d_ws;  // 147456 B fragment-ordered bf16 weights

  prep_w<<<dim3(288), dim3(256), 0, stream>>>(w, wt);
  conv_mfma<<<dim3(4, 127), dim3(256), 0, stream>>>(x, wt, b, out);
}

// Round 4
// 89.611 us; speedup vs baseline: 9.2718x; 1.1925x over previous
//
#include <hip/hip_runtime.h>
#include <stdint.h>

#define IN_C 64
#define HH 256
#define WW 256
#define HW (HH * WW)
#define OUT_C 128
#define OH 254
#define OW 254
#define OHW (OH * OW)

#define XR 4     // staged input rows (2 out rows + 2 halo)
#define XW 66    // staged input width (64 + 2 halo)
#define CPAD 72  // channel stride in shorts: 144 B (16B-aligned chunks, odd #16B -> spread)

typedef __attribute__((ext_vector_type(4))) float f32x4;
typedef __attribute__((ext_vector_type(8))) __bf16 bf16x8;

__device__ __forceinline__ unsigned short f2bf(float f) {
  union { float f; unsigned u; } v; v.f = f;
  unsigned r = v.u + 0x7FFFu + ((v.u >> 16) & 1u);  // RNE (inputs finite/normal)
  return (unsigned short)(r >> 16);
}

// Pre-shuffle weights into A-fragment order, bf16:
// wt[tap][ch][mt][lane][j] = bf16( W[o = mt*16 + (lane&15)][c = ch*32 + (lane>>4)*8 + j][ky][kx] )
// A-frag load is then a verbatim per-lane global_load_dwordx4 (L2-resident, no LDS).
__global__ void prep_w(const float* __restrict__ w, unsigned short* __restrict__ wt) {
  const int idx = blockIdx.x * 256 + threadIdx.x;
  if (idx >= 9 * 8192) return;
  const int j    = idx & 7;
  const int lane = (idx >> 3) & 63;
  const int mt   = (idx >> 9) & 7;
  const int ch   = (idx >> 12) & 1;
  const int tap  = idx >> 13;
  const int o = mt * 16 + (lane & 15);
  const int c = ch * 32 + (lane >> 4) * 8 + j;
  wt[idx] = f2bf(w[(o * IN_C + c) * 9 + tap]);
}

__global__ __launch_bounds__(256, 2) void conv_mfma(
    const float* __restrict__ x, const unsigned short* __restrict__ wt,
    const float* __restrict__ bias, float* __restrict__ out) {
  // Transposed input tile: Xs[r][xx][c], c contiguous
  __shared__ __align__(16) unsigned short Xs[XR * XW * CPAD];  // 38016 B

  const int tid  = threadIdx.x;
  const int wave = tid >> 6;
  const int lane = tid & 63;
  const int x0 = blockIdx.x * 64;   // 0,64,128,192 (last tile masks stores >= 254)
  const int y0 = blockIdx.y * 2;

  const int mhalf = wave & 1;   // which half of the 128 out-channels
  const int nhalf = wave >> 1;  // which of the 2 output rows
  const int nlane = lane & 15;
  const int quad  = lane >> 4;

  // Per-lane A-frag base: chunk c, sub-tile mt lives at Wp[(c*8 + mt)*64]
  const bf16x8* __restrict__ Wp = ((const bf16x8*)wt) + lane + (mhalf * 4) * 64;

  // issue chunk-0 A prefetch FIRST — in flight across the whole staging phase
  bf16x8 afA[4], afB[4];
#pragma unroll
  for (int mt = 0; mt < 4; ++mt) afA[mt] = Wp[mt * 64];

  // ---- stage Xs: Xs[r][xx][c] = bf16(x[c][y0+r][x0+xx])
  // thread = (cq = channel quad, xh = x hexadecile); writes are packed ds_write_b64
  // (4 channels per write) — per-instr bank pattern is the 4-pass minimum, conflict-free.
  {
    const int cq = tid & 15;   // channels cq*4 .. cq*4+3
    const int xh = tid >> 4;   // xx = xh*4 .. xh*4+3
    const float* bx = x + (y0 * WW + x0 + xh * 4);
#pragma unroll
    for (int r = 0; r < XR; ++r) {
      f32x4 vv[4];
#pragma unroll
      for (int cc = 0; cc < 4; ++cc)
        vv[cc] = *(const f32x4*)(bx + (cq * 4 + cc) * HW + r * WW);
#pragma unroll
      for (int xxi = 0; xxi < 4; ++xxi) {
        union { unsigned u[2]; } p;
        p.u[0] = (unsigned)f2bf(vv[0][xxi]) | ((unsigned)f2bf(vv[1][xxi]) << 16);
        p.u[1] = (unsigned)f2bf(vv[2][xxi]) | ((unsigned)f2bf(vv[3][xxi]) << 16);
        *(uint2*)&Xs[(r * XW + xh * 4 + xxi) * CPAD + cq * 4] = make_uint2(p.u[0], p.u[1]);
      }
    }
    // tail halo xx = 64, 65 (clamped reads only feed masked out-columns on last tile)
    if (tid < 128) {
      const int c = tid & 63;
      const int xxt = 64 + (tid >> 6);
      int xg = x0 + xxt;
      if (xg > WW - 1) xg = WW - 1;
#pragma unroll
      for (int r = 0; r < XR; ++r)
        Xs[(r * XW + xxt) * CPAD + c] = f2bf(x[c * HW + (y0 + r) * WW + xg]);
    }
  }

  // ---- accumulators initialized with bias (C/D row = quad*4 + reg = out-ch)
  f32x4 acc[4][4];
#pragma unroll
  for (int mt = 0; mt < 4; ++mt) {
    const f32x4 bv = *(const f32x4*)(bias + (mhalf * 4 + mt) * 16 + quad * 4);
#pragma unroll
    for (int nt = 0; nt < 4; ++nt) acc[mt][nt] = bv;
  }

  __syncthreads();  // Xs ready (single barrier in the kernel)

  // ---- 9 pairs of chunks (tap = pair; ch=0 via afA, ch=1 via afB), all indices static
#pragma unroll 1
  for (int pair = 0; pair < 9; ++pair) {
    const int ky = pair / 3;
    const int kx = pair - ky * 3;
    const int r = nhalf + ky;
    const unsigned short* xrow = &Xs[(r * XW + kx) * CPAD + quad * 8];

    // prefetch odd chunk (tap=pair, ch=1)
#pragma unroll
    for (int mt = 0; mt < 4; ++mt) afB[mt] = Wp[((2 * pair + 1) * 8 + mt) * 64];

    {  // compute even chunk (ch = 0) with afA
      bf16x8 bfr[4];
#pragma unroll
      for (int nt = 0; nt < 4; ++nt)
        bfr[nt] = *(const bf16x8*)&xrow[(nt * 16 + nlane) * CPAD];
#pragma unroll
      for (int mt = 0; mt < 4; ++mt)
#pragma unroll
        for (int nt = 0; nt < 4; ++nt)
          acc[mt][nt] = __builtin_amdgcn_mfma_f32_16x16x32_bf16(afA[mt], bfr[nt], acc[mt][nt], 0, 0, 0);
    }

    if (pair < 8) {  // prefetch next pair's even chunk (tap=pair+1, ch=0)
#pragma unroll
      for (int mt = 0; mt < 4; ++mt) afA[mt] = Wp[((2 * pair + 2) * 8 + mt) * 64];
    }

    {  // compute odd chunk (ch = 1) with afB
      bf16x8 bfr[4];
#pragma unroll
      for (int nt = 0; nt < 4; ++nt)
        bfr[nt] = *(const bf16x8*)&xrow[(nt * 16 + nlane) * CPAD + 32];
#pragma unroll
      for (int mt = 0; mt < 4; ++mt)
#pragma unroll
        for (int nt = 0; nt < 4; ++nt)
          acc[mt][nt] = __builtin_amdgcn_mfma_f32_16x16x32_bf16(afB[mt], bfr[nt], acc[mt][nt], 0, 0, 0);
    }
  }

  // ---- epilogue: C/D col = lane&15 (pixel), row = quad*4 + reg (out-ch); plain stores
  const int y = y0 + nhalf;
#pragma unroll
  for (int mt = 0; mt < 4; ++mt) {
    const int obase = (mhalf * 4 + mt) * 16 + quad * 4;
#pragma unroll
    for (int nt = 0; nt < 4; ++nt) {
      const int xc = x0 + nt * 16 + nlane;
      if (xc < OW) {
        float* dst = out + obase * OHW + y * OW + xc;
#pragma unroll
        for (int reg = 0; reg < 4; ++reg)
          dst[reg * OHW] = acc[mt][nt][reg];
      }
    }
  }
}

extern "C" void kernel_launch(void* const* d_in, const int* in_sizes, int n_in,
                              void* d_out, int out_size, void* d_ws, size_t ws_size,
                              hipStream_t stream) {
  const float* x = (const float*)d_in[0];
  const float* w = (const float*)d_in[1];
  const float* b = (const float*)d_in[2];
  float* out = (float*)d_out;
  unsigned short* wt = (unsigned short*)d_ws;  // 147456 B fragment-ordered bf16 weights

  prep_w<<<dim3(288), dim3(256), 0, stream>>>(w, wt);
  conv_mfma<<<dim3(4, 127), dim3(256), 0, stream>>>(x, wt, b, out);
}